// Round 5
// baseline (240.497 us; speedup 1.0000x reference)
//
#include <hip/hip_runtime.h>
#include <math.h>

typedef unsigned short u16;
typedef unsigned int u32;
typedef __attribute__((ext_vector_type(8))) short short8;
typedef __attribute__((ext_vector_type(4))) float f32x4;
typedef __attribute__((ext_vector_type(4))) u16 u16x4;
typedef __attribute__((ext_vector_type(4))) u32 u32x4;

#define AS1 __attribute__((address_space(1)))
#define AS3 __attribute__((address_space(3)))

// 0.125 * log2(e): QK^T scores scaled so softmax = exp2
#define QSCALE 0.18033688011112042f

__device__ __forceinline__ u16 f2bf(float f) {
  union { float f; u32 i; } u; u.f = f;
  u32 r = u.i + 0x7FFFu + ((u.i >> 16) & 1u);
  return (u16)(r >> 16);
}

__device__ __forceinline__ u32 pk_bf16(float a, float b) {
  u32 r;
  asm volatile("v_cvt_pk_bf16_f32 %0, %1, %2" : "=v"(r) : "v"(a), "v"(b));
  return r;
}

__device__ __forceinline__ void gl_lds16(const void* g, void* l) {
  __builtin_amdgcn_global_load_lds((const AS1 u32*)g, (AS3 u32*)l, 16, 0, 0);
}

// ---------------- RoPE table ----------------
__global__ void rope_table(float* __restrict__ cosT, float* __restrict__ sinT, int T) {
  int i = blockIdx.x * 256 + threadIdx.x;
  if (i >= T * 32) return;
  int t = i >> 5, j = i & 31;
  float inv = powf(10000.0f, -(float)j / 32.0f);
  float ang = (float)t * inv;
  cosT[i] = cosf(ang);
  sinT[i] = sinf(ang);
}

// ---------------- fused fp32 -> bf16 convert (x + 4 weights) ----------------
__global__ void cvt_all(const float* __restrict__ x,
                        const float* __restrict__ Wq, const float* __restrict__ Wk,
                        const float* __restrict__ Wv, const float* __restrict__ Wp,
                        u16* __restrict__ xb,
                        u16* __restrict__ Wqb, u16* __restrict__ Wkb,
                        u16* __restrict__ Wvb, u16* __restrict__ Wpb,
                        int n4x) {
  int i = blockIdx.x * 256 + threadIdx.x;
  const float* src; u16* dst; int off;
  if (i < n4x) { src = x; dst = xb; off = i; }
  else {
    int wi = i - n4x;
    int sel = wi >> 18;            // CC/4 = 2^18
    off = wi & ((1 << 18) - 1);
    src = sel == 0 ? Wq : sel == 1 ? Wk : sel == 2 ? Wv : Wp;
    dst = sel == 0 ? Wqb : sel == 1 ? Wkb : sel == 2 ? Wvb : Wpb;
  }
  float4 v = ((const float4*)src)[off];
  u16x4 o = { f2bf(v.x), f2bf(v.y), f2bf(v.z), f2bf(v.w) };
  ((u16x4*)dst)[off] = o;
}

// ---------------- fused QKV GEMM (bf16 MFMA) with RoPE epilogue ----------------
__global__ __launch_bounds__(256, 2) void gemm_qkv(
    const u16* __restrict__ xb,
    const u16* __restrict__ Wqb, const u16* __restrict__ Wkb, const u16* __restrict__ Wvb,
    const float* __restrict__ bq, const float* __restrict__ bk, const float* __restrict__ bv,
    const float* __restrict__ cosT, const float* __restrict__ sinT,
    u16* __restrict__ Qb, u16* __restrict__ Kb, u16* __restrict__ Vb) {
  const int K = 1024, N = 1024;
  __shared__ __attribute__((aligned(16))) u16 As[128 * 32];
  __shared__ __attribute__((aligned(16))) u16 Bs[128 * 32];
  const int tid = threadIdx.x;
  const int lane = tid & 63;
  const int hi = lane >> 4, cc = lane & 15;
  const int w = tid >> 6, wm = w >> 1, wn = w & 1;
  const int sel = blockIdx.x >> 3;
  const int row0 = blockIdx.y * 128, col0 = (blockIdx.x & 7) * 128;
  const u16* W = sel == 0 ? Wqb : sel == 1 ? Wkb : Wvb;
  const float* bias = sel == 0 ? bq : sel == 1 ? bk : bv;
  u16* Out = sel == 0 ? Qb : sel == 1 ? Kb : Vb;

  const int lr = tid >> 2;
  const int lk = (tid & 3) * 8;
  const u16* Ag0 = xb + (size_t)(row0 + lr) * K + lk;
  const u16* Ag1 = xb + (size_t)(row0 + 64 + lr) * K + lk;
  const u16* Wg0 = W + (size_t)(col0 + lr) * K + lk;
  const u16* Wg1 = W + (size_t)(col0 + 64 + lr) * K + lk;
  u16* Al0 = As + tid * 8;
  u16* Al1 = As + 2048 + tid * 8;
  u16* Bl0 = Bs + tid * 8;
  u16* Bl1 = Bs + 2048 + tid * 8;

  f32x4 acc[4][4];
#pragma unroll
  for (int m = 0; m < 4; ++m)
#pragma unroll
    for (int n = 0; n < 4; ++n) acc[m][n] = f32x4{0.f, 0.f, 0.f, 0.f};

  for (int k0 = 0; k0 < K; k0 += 32) {
    __syncthreads();
    gl_lds16(Ag0 + k0, Al0);
    gl_lds16(Ag1 + k0, Al1);
    gl_lds16(Wg0 + k0, Bl0);
    gl_lds16(Wg1 + k0, Bl1);
    __syncthreads();
    short8 a[4], b[4];
#pragma unroll
    for (int m = 0; m < 4; ++m)
      a[m] = *(const short8*)(As + (wm * 64 + m * 16 + cc) * 32 + hi * 8);
#pragma unroll
    for (int n = 0; n < 4; ++n)
      b[n] = *(const short8*)(Bs + (wn * 64 + n * 16 + cc) * 32 + hi * 8);
#pragma unroll
    for (int m = 0; m < 4; ++m)
#pragma unroll
      for (int n = 0; n < 4; ++n)
        acc[m][n] = __builtin_amdgcn_mfma_f32_16x16x32_bf16(a[m], b[n], acc[m][n], 0, 0, 0);
  }

  if (sel < 2) {
    const float qs = (sel == 0) ? QSCALE : 1.0f;
#pragma unroll
    for (int n = 0; n < 4; ++n) {
      const int col = col0 + wn * 64 + n * 16 + cc;
      const int j = (col & 63) >> 1;
      const float bb = bias[col];
#pragma unroll
      for (int m = 0; m < 4; ++m) {
        const int rw = row0 + wm * 64 + m * 16 + hi * 4;
#pragma unroll
        for (int r = 0; r < 4; ++r) {
          const int row = rw + r;
          const int t = row & 2047;
          float v = acc[m][n][r] + bb;
          float pv = __shfl_xor(v, 1);
          float c = cosT[t * 32 + j], s = sinT[t * 32 + j];
          float oo = (cc & 1) ? (s * pv + c * v) : (c * v - s * pv);
          Out[(size_t)row * N + col] = f2bf(oo * qs);
        }
      }
    }
  } else {
#pragma unroll
    for (int n = 0; n < 4; ++n) {
      const int col = col0 + wn * 64 + n * 16 + cc;
      const float bb = bias[col];
#pragma unroll
      for (int m = 0; m < 4; ++m) {
        const int rw = row0 + wm * 64 + m * 16 + hi * 4;
#pragma unroll
        for (int r = 0; r < 4; ++r)
          Out[(size_t)(rw + r) * N + col] = f2bf(acc[m][n][r] + bb);
      }
    }
  }
}

// ---------------- barrier-free MFMA causal flash attention ----------------
// 4 independent waves/block, each owns 32 q rows with private LDS (Vt 8KB + Ps 4KB).
// K fragments read directly from global (L2-resident). Zero __syncthreads.
__global__ __launch_bounds__(256, 3) void flash_mfma(
    const u16* __restrict__ Qb, const u16* __restrict__ Kb,
    const u16* __restrict__ Vb, u16* __restrict__ Yb) {
  const int T = 2048, C = 1024;
  __shared__ __attribute__((aligned(16))) u16 VtAll[4][64 * 64];  // per-wave V^T [d][key]
  __shared__ __attribute__((aligned(16))) u16 PsAll[4][32 * 64];  // per-wave P [q][key]

  const int tid = threadIdx.x;
  const int lane = tid & 63;
  const int hi = lane >> 4, cc = lane & 15;
  const int w = tid >> 6;
  const int qt = (int)gridDim.x - 1 - (int)blockIdx.x;  // longest blocks first
  const int bh = blockIdx.y;
  const size_t hbase = (size_t)(bh >> 4) * T * C + (size_t)(bh & 15) * 64;
  const int q0w = qt * 128 + w * 32;

  // Q fragments (B-operand, pre-scaled by QSCALE): [qh][kc2]
  short8 qa[2][2];
#pragma unroll
  for (int qh = 0; qh < 2; ++qh) {
    const u16* qp = Qb + hbase + (size_t)(q0w + qh * 16 + cc) * C + hi * 8;
    qa[qh][0] = *(const short8*)qp;
    qa[qh][1] = *(const short8*)(qp + 32);
  }

  f32x4 o[4][2];
#pragma unroll
  for (int nt = 0; nt < 4; ++nt)
#pragma unroll
    for (int qh = 0; qh < 2; ++qh) o[nt][qh] = f32x4{0.f, 0.f, 0.f, 0.f};
  float mrow[2] = {-1e30f, -1e30f};
  float lsum[2] = {0.f, 0.f};

  // V staging map: lane covers keys vkey0..vkey0+7, dims vd0..vd0+7
  const int vkey0 = (lane & 7) * 8;
  const int vd0 = (lane >> 3) * 8;
  const u16* vgb = Vb + hbase + (size_t)vkey0 * C + vd0;
  const u16* kgb = Kb + hbase;

  char* VtB = (char*)(VtAll[w]);
  char* PsB = (char*)(PsAll[w]);

  const int ktmax = (q0w + 31) >> 6;

  // prefetch V tile 0 into regs
  short8 vr_[8];
#pragma unroll
  for (int j = 0; j < 8; ++j)
    vr_[j] = *(const short8*)(vgb + (size_t)j * C);

  for (int kt = 0; kt <= ktmax; ++kt) {
    // K fragments for this tile: direct from global (no LDS)
    short8 kf[4][2];
#pragma unroll
    for (int nt = 0; nt < 4; ++nt) {
      const u16* kp = kgb + (size_t)(kt * 64 + nt * 16 + cc) * C + hi * 8;
      kf[nt][0] = *(const short8*)kp;
      kf[nt][1] = *(const short8*)(kp + 32);
    }

    // stage prefetched V tile into private Vt (transposed), b128 writes
#pragma unroll
    for (int i = 0; i < 8; ++i) {
      const int d = vd0 + i;
      u32 w0 = (u32)(u16)vr_[0][i] | ((u32)(u16)vr_[1][i] << 16);
      u32 w1 = (u32)(u16)vr_[2][i] | ((u32)(u16)vr_[3][i] << 16);
      u32 w2 = (u32)(u16)vr_[4][i] | ((u32)(u16)vr_[5][i] << 16);
      u32 w3 = (u32)(u16)vr_[6][i] | ((u32)(u16)vr_[7][i] << 16);
      u32x4 pkv = {w0, w1, w2, w3};
      *(u32x4*)(VtB + ((d * 128 + vkey0 * 2) ^ ((d & 7) << 4))) = pkv;
    }

    // prefetch next V tile (clamped)
    {
      const size_t koff = (size_t)((kt < ktmax ? kt + 1 : kt) * 64) * C;
#pragma unroll
      for (int j = 0; j < 8; ++j)
        vr_[j] = *(const short8*)(vgb + koff + (size_t)j * C);
    }

    const bool diagt = (kt == ktmax) || (kt * 64 + 63 > q0w);

    // per q-half: QK^T -> softmax -> P stage
#pragma unroll
    for (int qh = 0; qh < 2; ++qh) {
      f32x4 s[4];
#pragma unroll
      for (int nt = 0; nt < 4; ++nt) {
        f32x4 z = f32x4{0.f, 0.f, 0.f, 0.f};
        z = __builtin_amdgcn_mfma_f32_16x16x32_bf16(kf[nt][0], qa[qh][0], z, 0, 0, 0);
        z = __builtin_amdgcn_mfma_f32_16x16x32_bf16(kf[nt][1], qa[qh][1], z, 0, 0, 0);
        s[nt] = z;
      }

      if (diagt) {
        const int qoff = q0w + qh * 16 + cc - kt * 64;
#pragma unroll
        for (int nt = 0; nt < 4; ++nt)
#pragma unroll
          for (int r = 0; r < 4; ++r) {
            const int key = nt * 16 + hi * 4 + r;
            if (key > qoff) s[nt][r] = -1e30f;
          }
      }

      float tm = s[0][0];
#pragma unroll
      for (int nt = 0; nt < 4; ++nt)
#pragma unroll
        for (int r = 0; r < 4; ++r) tm = fmaxf(tm, s[nt][r]);
      tm = fmaxf(tm, __shfl_xor(tm, 16));
      tm = fmaxf(tm, __shfl_xor(tm, 32));

      const bool need = tm > mrow[qh] + 8.0f;   // defer-max threshold
      float corr = 1.0f;
      if (need) { corr = exp2f(mrow[qh] - tm); mrow[qh] = tm; }

      float p[16];
      float psum = 0.f;
#pragma unroll
      for (int nt = 0; nt < 4; ++nt)
#pragma unroll
        for (int r = 0; r < 4; ++r) {
          float e = exp2f(s[nt][r] - mrow[qh]);
          p[nt * 4 + r] = e;
          psum += e;
        }
      psum += __shfl_xor(psum, 16);
      psum += __shfl_xor(psum, 32);
      lsum[qh] = lsum[qh] * corr + psum;
      if (__any(need)) {
#pragma unroll
        for (int nt = 0; nt < 4; ++nt) o[nt][qh] *= corr;
      }

      // stage P[q][key] as 4x ds_write_b64 (swizzled)
      const int pr = qh * 16 + cc;
      const int psw = (pr & 7) << 4;
#pragma unroll
      for (int nt = 0; nt < 4; ++nt) {
        u32 lo = pk_bf16(p[nt * 4 + 0], p[nt * 4 + 1]);
        u32 hi2 = pk_bf16(p[nt * 4 + 2], p[nt * 4 + 3]);
        u32 pair[2] = {lo, hi2};
        *(unsigned long long*)(PsB + ((pr * 128 + nt * 32 + hi * 8) ^ psw)) =
            *(const unsigned long long*)pair;
      }
    }

    // O^T += V^T P^T
#pragma unroll
    for (int kc = 0; kc < 2; ++kc) {
      short8 pa[2];
#pragma unroll
      for (int qh = 0; qh < 2; ++qh) {
        const int pr = qh * 16 + cc;
        pa[qh] = *(const short8*)(PsB + ((pr * 128 + kc * 64 + hi * 16) ^ ((pr & 7) << 4)));
      }
#pragma unroll
      for (int nt = 0; nt < 4; ++nt) {
        const int vr = nt * 16 + cc;
        short8 vb = *(const short8*)(VtB + ((vr * 128 + kc * 64 + hi * 16) ^ ((vr & 7) << 4)));
#pragma unroll
        for (int qh = 0; qh < 2; ++qh)
          o[nt][qh] = __builtin_amdgcn_mfma_f32_16x16x32_bf16(vb, pa[qh], o[nt][qh], 0, 0, 0);
      }
    }
  }

#pragma unroll
  for (int qh = 0; qh < 2; ++qh) {
    const float invl = 1.0f / lsum[qh];
#pragma unroll
    for (int nt = 0; nt < 4; ++nt) {
      u16x4 y = { f2bf(o[nt][qh][0] * invl), f2bf(o[nt][qh][1] * invl),
                  f2bf(o[nt][qh][2] * invl), f2bf(o[nt][qh][3] * invl) };
      *(u16x4*)(Yb + hbase + (size_t)(q0w + qh * 16 + cc) * C + nt * 16 + hi * 4) = y;
    }
  }
}

// ---------------- proj GEMM: BN=64, fp32 out ----------------
__global__ __launch_bounds__(256, 2) void gemm_proj(
    const u16* __restrict__ A, const u16* __restrict__ W,
    const float* __restrict__ bias, float* __restrict__ Out) {
  const int K = 1024, N = 1024;
  __shared__ __attribute__((aligned(16))) u16 As[128 * 32];
  __shared__ __attribute__((aligned(16))) u16 Bs[64 * 32];
  const int tid = threadIdx.x;
  const int lane = tid & 63;
  const int hi = lane >> 4, cc = lane & 15;
  const int w = tid >> 6, wm = w >> 1, wn = w & 1;
  const int row0 = blockIdx.y * 128, col0 = blockIdx.x * 64;

  const int lr = tid >> 2;
  const int lk = (tid & 3) * 8;
  const u16* Ag0 = A + (size_t)(row0 + lr) * K + lk;
  const u16* Ag1 = A + (size_t)(row0 + 64 + lr) * K + lk;
  const u16* Wg0 = W + (size_t)(col0 + lr) * K + lk;
  u16* Al0 = As + tid * 8;
  u16* Al1 = As + 2048 + tid * 8;
  u16* Bl0 = Bs + tid * 8;

  f32x4 acc[4][2];
#pragma unroll
  for (int m = 0; m < 4; ++m)
#pragma unroll
    for (int n = 0; n < 2; ++n) acc[m][n] = f32x4{0.f, 0.f, 0.f, 0.f};

  for (int k0 = 0; k0 < K; k0 += 32) {
    __syncthreads();
    gl_lds16(Ag0 + k0, Al0);
    gl_lds16(Ag1 + k0, Al1);
    gl_lds16(Wg0 + k0, Bl0);
    __syncthreads();
    short8 a[4], b[2];
#pragma unroll
    for (int m = 0; m < 4; ++m)
      a[m] = *(const short8*)(As + (wm * 64 + m * 16 + cc) * 32 + hi * 8);
#pragma unroll
    for (int n = 0; n < 2; ++n)
      b[n] = *(const short8*)(Bs + (wn * 32 + n * 16 + cc) * 32 + hi * 8);
#pragma unroll
    for (int m = 0; m < 4; ++m)
#pragma unroll
      for (int n = 0; n < 2; ++n)
        acc[m][n] = __builtin_amdgcn_mfma_f32_16x16x32_bf16(a[m], b[n], acc[m][n], 0, 0, 0);
  }

#pragma unroll
  for (int n = 0; n < 2; ++n) {
    const int col = col0 + wn * 32 + n * 16 + cc;
    const float bb = bias[col];
#pragma unroll
    for (int m = 0; m < 4; ++m) {
      const int rw = row0 + wm * 64 + m * 16 + hi * 4;
#pragma unroll
      for (int r = 0; r < 4; ++r)
        Out[(size_t)(rw + r) * N + col] = acc[m][n][r] + bb;
    }
  }
}

extern "C" void kernel_launch(void* const* d_in, const int* in_sizes, int n_in,
                              void* d_out, int out_size, void* d_ws, size_t ws_size,
                              hipStream_t stream) {
  const float* x  = (const float*)d_in[0];
  const float* Wq = (const float*)d_in[1];
  const float* bq = (const float*)d_in[2];
  const float* Wk = (const float*)d_in[3];
  const float* bk = (const float*)d_in[4];
  const float* Wv = (const float*)d_in[5];
  const float* bv = (const float*)d_in[6];
  const float* Wp = (const float*)d_in[7];
  const float* bp = (const float*)d_in[8];
  float* out = (float*)d_out;

  const int B = 2, T = 2048, C = 1024;
  const int M = B * T;
  const size_t MC = (size_t)M * C;
  const size_t CC = (size_t)C * C;

  char* p = (char*)d_ws;
  u16* xb  = (u16*)p;  p += MC * 2;    // reused as Y after QKV GEMM
  u16* Wqb = (u16*)p;  p += CC * 2;
  u16* Wkb = (u16*)p;  p += CC * 2;
  u16* Wvb = (u16*)p;  p += CC * 2;
  u16* Wpb = (u16*)p;  p += CC * 2;
  u16* Qbb = (u16*)p;  p += MC * 2;
  u16* Kbb = (u16*)p;  p += MC * 2;
  u16* Vbb = (u16*)p;  p += MC * 2;
  float* cosT = (float*)p; p += (size_t)T * 32 * 4;
  float* sinT = (float*)p; p += (size_t)T * 32 * 4;

  rope_table<<<T * 32 / 256, 256, 0, stream>>>(cosT, sinT, T);
  const int n4x = (int)(MC / 4);
  const int n4tot = n4x + 4 * (int)(CC / 4);
  cvt_all<<<n4tot / 256, 256, 0, stream>>>(x, Wq, Wk, Wv, Wp, xb, Wqb, Wkb, Wvb, Wpb, n4x);

  dim3 gq(24, M / 128);
  gemm_qkv<<<gq, 256, 0, stream>>>(xb, Wqb, Wkb, Wvb, bq, bk, bv, cosT, sinT, Qbb, Kbb, Vbb);

  dim3 fg(T / 128, B * 16);
  flash_mfma<<<fg, 256, 0, stream>>>(Qbb, Kbb, Vbb, xb);   // Y -> xb (reuse)

  dim3 gp(C / 64, M / 128);
  gemm_proj<<<gp, 256, 0, stream>>>(xb, Wpb, bp, out);
}

// Round 7
// 161.774 us; speedup vs baseline: 1.4866x; 1.4866x over previous
//
#include <hip/hip_runtime.h>
#include <math.h>

typedef unsigned short u16;
typedef unsigned int u32;
typedef __attribute__((ext_vector_type(8))) short short8;
typedef __attribute__((ext_vector_type(4))) float f32x4;
typedef __attribute__((ext_vector_type(4))) u16 u16x4;
typedef __attribute__((ext_vector_type(4))) u32 u32x4;

#define AS1 __attribute__((address_space(1)))
#define AS3 __attribute__((address_space(3)))

// 0.125 * log2(e): QK^T scores scaled so softmax = exp2
#define QSCALE 0.18033688011112042f

__device__ __forceinline__ u16 f2bf(float f) {
  union { float f; u32 i; } u; u.f = f;
  u32 r = u.i + 0x7FFFu + ((u.i >> 16) & 1u);
  return (u16)(r >> 16);
}

__device__ __forceinline__ u32 pk_bf16(float a, float b) {
  u32 r;
  asm volatile("v_cvt_pk_bf16_f32 %0, %1, %2" : "=v"(r) : "v"(a), "v"(b));
  return r;
}

__device__ __forceinline__ void gl_lds16(const void* g, void* l) {
  __builtin_amdgcn_global_load_lds((const AS1 u32*)g, (AS3 u32*)l, 16, 0, 0);
}

// ---------------- RoPE table ----------------
__global__ void rope_table(float* __restrict__ cosT, float* __restrict__ sinT, int T) {
  int i = blockIdx.x * 256 + threadIdx.x;
  if (i >= T * 32) return;
  int t = i >> 5, j = i & 31;
  float inv = powf(10000.0f, -(float)j / 32.0f);
  float ang = (float)t * inv;
  cosT[i] = cosf(ang);
  sinT[i] = sinf(ang);
}

// ---------------- fused fp32 -> bf16 convert (x + 4 weights) ----------------
__global__ void cvt_all(const float* __restrict__ x,
                        const float* __restrict__ Wq, const float* __restrict__ Wk,
                        const float* __restrict__ Wv, const float* __restrict__ Wp,
                        u16* __restrict__ xb,
                        u16* __restrict__ Wqb, u16* __restrict__ Wkb,
                        u16* __restrict__ Wvb, u16* __restrict__ Wpb,
                        int n4x) {
  int i = blockIdx.x * 256 + threadIdx.x;
  const float* src; u16* dst; int off;
  if (i < n4x) { src = x; dst = xb; off = i; }
  else {
    int wi = i - n4x;
    int sel = wi >> 18;            // CC/4 = 2^18
    off = wi & ((1 << 18) - 1);
    src = sel == 0 ? Wq : sel == 1 ? Wk : sel == 2 ? Wv : Wp;
    dst = sel == 0 ? Wqb : sel == 1 ? Wkb : sel == 2 ? Wvb : Wpb;
  }
  float4 v = ((const float4*)src)[off];
  u16x4 o = { f2bf(v.x), f2bf(v.y), f2bf(v.z), f2bf(v.w) };
  ((u16x4*)dst)[off] = o;
}

// ---------------- fused QKV GEMM (bf16 MFMA) with RoPE epilogue ----------------
__global__ __launch_bounds__(256, 2) void gemm_qkv(
    const u16* __restrict__ xb,
    const u16* __restrict__ Wqb, const u16* __restrict__ Wkb, const u16* __restrict__ Wvb,
    const float* __restrict__ bq, const float* __restrict__ bk, const float* __restrict__ bv,
    const float* __restrict__ cosT, const float* __restrict__ sinT,
    u16* __restrict__ Qb, u16* __restrict__ Kb, u16* __restrict__ Vb) {
  const int K = 1024, N = 1024;
  __shared__ __attribute__((aligned(16))) u16 As[128 * 32];
  __shared__ __attribute__((aligned(16))) u16 Bs[128 * 32];
  const int tid = threadIdx.x;
  const int lane = tid & 63;
  const int hi = lane >> 4, cc = lane & 15;
  const int w = tid >> 6, wm = w >> 1, wn = w & 1;
  const int sel = blockIdx.x >> 3;
  const int row0 = blockIdx.y * 128, col0 = (blockIdx.x & 7) * 128;
  const u16* W = sel == 0 ? Wqb : sel == 1 ? Wkb : Wvb;
  const float* bias = sel == 0 ? bq : sel == 1 ? bk : bv;
  u16* Out = sel == 0 ? Qb : sel == 1 ? Kb : Vb;

  const int lr = tid >> 2;
  const int lk = (tid & 3) * 8;
  const u16* Ag0 = xb + (size_t)(row0 + lr) * K + lk;
  const u16* Ag1 = xb + (size_t)(row0 + 64 + lr) * K + lk;
  const u16* Wg0 = W + (size_t)(col0 + lr) * K + lk;
  const u16* Wg1 = W + (size_t)(col0 + 64 + lr) * K + lk;
  u16* Al0 = As + tid * 8;
  u16* Al1 = As + 2048 + tid * 8;
  u16* Bl0 = Bs + tid * 8;
  u16* Bl1 = Bs + 2048 + tid * 8;

  f32x4 acc[4][4];
#pragma unroll
  for (int m = 0; m < 4; ++m)
#pragma unroll
    for (int n = 0; n < 4; ++n) acc[m][n] = f32x4{0.f, 0.f, 0.f, 0.f};

  for (int k0 = 0; k0 < K; k0 += 32) {
    __syncthreads();
    gl_lds16(Ag0 + k0, Al0);
    gl_lds16(Ag1 + k0, Al1);
    gl_lds16(Wg0 + k0, Bl0);
    gl_lds16(Wg1 + k0, Bl1);
    __syncthreads();
    short8 a[4], b[4];
#pragma unroll
    for (int m = 0; m < 4; ++m)
      a[m] = *(const short8*)(As + (wm * 64 + m * 16 + cc) * 32 + hi * 8);
#pragma unroll
    for (int n = 0; n < 4; ++n)
      b[n] = *(const short8*)(Bs + (wn * 64 + n * 16 + cc) * 32 + hi * 8);
#pragma unroll
    for (int m = 0; m < 4; ++m)
#pragma unroll
      for (int n = 0; n < 4; ++n)
        acc[m][n] = __builtin_amdgcn_mfma_f32_16x16x32_bf16(a[m], b[n], acc[m][n], 0, 0, 0);
  }

  if (sel < 2) {
    const float qs = (sel == 0) ? QSCALE : 1.0f;
#pragma unroll
    for (int n = 0; n < 4; ++n) {
      const int col = col0 + wn * 64 + n * 16 + cc;
      const int j = (col & 63) >> 1;
      const float bb = bias[col];
#pragma unroll
      for (int m = 0; m < 4; ++m) {
        const int rw = row0 + wm * 64 + m * 16 + hi * 4;
#pragma unroll
        for (int r = 0; r < 4; ++r) {
          const int row = rw + r;
          const int t = row & 2047;
          float v = acc[m][n][r] + bb;
          float pv = __shfl_xor(v, 1);
          float c = cosT[t * 32 + j], s = sinT[t * 32 + j];
          float oo = (cc & 1) ? (s * pv + c * v) : (c * v - s * pv);
          Out[(size_t)row * N + col] = f2bf(oo * qs);
        }
      }
    }
  } else {
#pragma unroll
    for (int n = 0; n < 4; ++n) {
      const int col = col0 + wn * 64 + n * 16 + cc;
      const float bb = bias[col];
#pragma unroll
      for (int m = 0; m < 4; ++m) {
        const int rw = row0 + wm * 64 + m * 16 + hi * 4;
#pragma unroll
        for (int r = 0; r < 4; ++r)
          Out[(size_t)(rw + r) * N + col] = f2bf(acc[m][n][r] + bb);
      }
    }
  }
}

// ---------------- MFMA causal flash attention ----------------
// 64 q/block (4 waves x 16 q), double-buffered block-cooperative K/V staging,
// one raw s_barrier per k-tile (no vmcnt drain), in-register P via ds_bpermute
// with DEST-side nt selection (source lane can't know dest's hi>>1).
__global__ __launch_bounds__(256, 3) void flash_mfma(
    const u16* __restrict__ Qb, const u16* __restrict__ Kb,
    const u16* __restrict__ Vb, u16* __restrict__ Yb) {
  const int T = 2048, C = 1024;
  // [buf][ Ks 8KB | Vt 8KB ]
  __shared__ __attribute__((aligned(16))) char lds[2][16384];

  const int tid = threadIdx.x;
  const int lane = tid & 63;
  const int hi = lane >> 4, cc = lane & 15;
  const int w = tid >> 6;
  const int qt = (int)gridDim.x - 1 - (int)blockIdx.x;  // longest blocks first
  const int bh = blockIdx.y;
  const size_t hbase = (size_t)(bh >> 4) * T * C + (size_t)(bh & 15) * 64;
  const int q0w = qt * 64 + w * 16;
  const int ktmax = qt;

  // Q fragment (B-operand, pre-scaled by QSCALE)
  short8 qa0, qa1;
  {
    const u16* qp = Qb + hbase + (size_t)(q0w + cc) * C + hi * 8;
    qa0 = *(const short8*)qp;
    qa1 = *(const short8*)(qp + 32);
  }

  f32x4 o[4];
#pragma unroll
  for (int nt = 0; nt < 4; ++nt) o[nt] = f32x4{0.f, 0.f, 0.f, 0.f};
  float mrow = -1e30f, lsum = 0.f;

  // staging maps (block-cooperative, 256 threads)
  const int krow = tid >> 2, kcol = (tid & 3) * 16;       // K: 64 rows x 128B
  const int vd0 = (tid & 31) * 2, vkey0 = (tid >> 5) * 8; // V: coalesced u32 loads
  const u16* kgp = Kb + hbase + (size_t)krow * C + kcol;
  const u16* vgp = Vb + hbase + (size_t)vkey0 * C + vd0;

  short8 kr0, kr1;
  u32 vr_[8];

  auto LOADT = [&](int kt) {
    const size_t off = (size_t)(kt * 64) * C;
    kr0 = *(const short8*)(kgp + off);
    kr1 = *(const short8*)(kgp + off + 8);
#pragma unroll
    for (int j = 0; j < 8; ++j)
      vr_[j] = *(const u32*)(vgp + off + (size_t)j * C);
  };

  auto WRITET = [&](int buf) {
    char* KsB = lds[buf];
    char* VtB = lds[buf] + 8192;
    const int kb = krow * 128 + kcol * 2;
    const int ksw = (krow & 7) << 4;
    *(short8*)(KsB + (kb ^ ksw)) = kr0;
    *(short8*)(KsB + ((kb + 16) ^ ksw)) = kr1;
    // transpose-pack V: rows d0 (low halves) and d0+1 (high halves)
    u32 lo0 = (vr_[0] & 0xFFFFu) | (vr_[1] << 16);
    u32 lo1 = (vr_[2] & 0xFFFFu) | (vr_[3] << 16);
    u32 lo2 = (vr_[4] & 0xFFFFu) | (vr_[5] << 16);
    u32 lo3 = (vr_[6] & 0xFFFFu) | (vr_[7] << 16);
    u32 hh0 = (vr_[0] >> 16) | (vr_[1] & 0xFFFF0000u);
    u32 hh1 = (vr_[2] >> 16) | (vr_[3] & 0xFFFF0000u);
    u32 hh2 = (vr_[4] >> 16) | (vr_[5] & 0xFFFF0000u);
    u32 hh3 = (vr_[6] >> 16) | (vr_[7] & 0xFFFF0000u);
    const int d1 = vd0 + 1;
    u32x4 vlo = {lo0, lo1, lo2, lo3};
    u32x4 vhi = {hh0, hh1, hh2, hh3};
    *(u32x4*)(VtB + ((vd0 * 128 + vkey0 * 2) ^ ((vd0 & 7) << 4))) = vlo;
    *(u32x4*)(VtB + ((d1 * 128 + vkey0 * 2) ^ ((d1 & 7) << 4))) = vhi;
  };

  // bpermute source-lane addresses (byte units = lane*4)
  const int addrA = (((2 * hi) & 3) * 16 + cc) * 4;       // lane (2*(hi&1),   cc)
  const int addrB = (((2 * hi + 1) & 3) * 16 + cc) * 4;   // lane (2*(hi&1)+1, cc)

  // prologue: stage tile 0, prefetch tile 1
  LOADT(0);
  WRITET(0);
  if (ktmax >= 1) LOADT(1);
  asm volatile("s_waitcnt lgkmcnt(0)" ::: "memory");
  __builtin_amdgcn_s_barrier();

  for (int kt = 0; kt <= ktmax; ++kt) {
    const int cur = kt & 1;
    if (kt < ktmax) {
      WRITET(cur ^ 1);                 // stage tile kt+1 (regs from last iter)
      if (kt + 1 < ktmax) LOADT(kt + 2);  // prefetch tile kt+2 (survives barrier)
    }

    char* KsB = lds[cur];
    char* VtB = lds[cur] + 8192;

    // K fragments
    short8 kf[4][2];
    const int ksw2 = (cc & 7) << 4;
#pragma unroll
    for (int nt = 0; nt < 4; ++nt) {
      const int kb = (nt * 16 + cc) * 128 + hi * 16;
      kf[nt][0] = *(const short8*)(KsB + (kb ^ ksw2));
      kf[nt][1] = *(const short8*)(KsB + ((kb + 64) ^ ksw2));
    }

    // S^T = K Q^T : lane holds 16 keys for q = cc
    f32x4 s[4];
#pragma unroll
    for (int nt = 0; nt < 4; ++nt) {
      f32x4 z = f32x4{0.f, 0.f, 0.f, 0.f};
      z = __builtin_amdgcn_mfma_f32_16x16x32_bf16(kf[nt][0], qa0, z, 0, 0, 0);
      z = __builtin_amdgcn_mfma_f32_16x16x32_bf16(kf[nt][1], qa1, z, 0, 0, 0);
      s[nt] = z;
    }

    if (kt == ktmax) {   // diagonal tile: mask local key > local q
      const int qoff = w * 16 + cc;
#pragma unroll
      for (int nt = 0; nt < 4; ++nt)
#pragma unroll
        for (int r = 0; r < 4; ++r) {
          const int key = nt * 16 + hi * 4 + r;
          if (key > qoff) s[nt][r] = -1e30f;
        }
    }

    // softmax over 64 keys (16 in-lane + 2 cross-hi shuffles), exp2 domain
    float tm = s[0][0];
#pragma unroll
    for (int nt = 0; nt < 4; ++nt)
#pragma unroll
      for (int r = 0; r < 4; ++r) tm = fmaxf(tm, s[nt][r]);
    tm = fmaxf(tm, __shfl_xor(tm, 16));
    tm = fmaxf(tm, __shfl_xor(tm, 32));

    const bool need = tm > mrow + 8.0f;   // defer-max threshold
    float corr = 1.0f;
    if (need) { corr = exp2f(mrow - tm); mrow = tm; }

    float p[16];
    float psum = 0.f;
#pragma unroll
    for (int nt = 0; nt < 4; ++nt)
#pragma unroll
      for (int r = 0; r < 4; ++r) {
        float e = exp2f(s[nt][r] - mrow);
        p[nt * 4 + r] = e;
        psum += e;
      }
    psum += __shfl_xor(psum, 16);
    psum += __shfl_xor(psum, 32);
    lsum = lsum * corr + psum;
    if (__any(need)) {
#pragma unroll
      for (int nt = 0; nt < 4; ++nt) o[nt] *= corr;
    }

    // pack P to bf16 pairs: W[nt*2+s] = keys nt*16 + hi*4 + {2s, 2s+1}
    u32 W[8];
#pragma unroll
    for (int nt = 0; nt < 4; ++nt) {
      W[nt * 2 + 0] = pk_bf16(p[nt * 4 + 0], p[nt * 4 + 1]);
      W[nt * 2 + 1] = pk_bf16(p[nt * 4 + 2], p[nt * 4 + 3]);
    }

    // O^T += V^T P^T ; B-operand for call kc needs keys kc*32+hi*8+0..7:
    // words W[2nt'], W[2nt'+1] with nt' = 2kc + (hi>>1) from lanes
    // 2*(hi&1), 2*(hi&1)+1. nt' depends on DEST hi>>1, which the source
    // lane cannot evaluate -> fetch both nt candidates, select at dest.
#pragma unroll
    for (int kc = 0; kc < 2; ++kc) {
      u32 c0 = (u32)__builtin_amdgcn_ds_bpermute(addrA, (int)W[4 * kc + 0]);
      u32 c1 = (u32)__builtin_amdgcn_ds_bpermute(addrA, (int)W[4 * kc + 1]);
      u32 c2 = (u32)__builtin_amdgcn_ds_bpermute(addrA, (int)W[4 * kc + 2]);
      u32 c3 = (u32)__builtin_amdgcn_ds_bpermute(addrA, (int)W[4 * kc + 3]);
      u32 d0 = (u32)__builtin_amdgcn_ds_bpermute(addrB, (int)W[4 * kc + 0]);
      u32 d1 = (u32)__builtin_amdgcn_ds_bpermute(addrB, (int)W[4 * kc + 1]);
      u32 d2 = (u32)__builtin_amdgcn_ds_bpermute(addrB, (int)W[4 * kc + 2]);
      u32 d3 = (u32)__builtin_amdgcn_ds_bpermute(addrB, (int)W[4 * kc + 3]);
      const bool sel2 = (hi & 2) != 0;
      union { u32 u[4]; short8 v; } pu;
      pu.u[0] = sel2 ? c2 : c0;
      pu.u[1] = sel2 ? c3 : c1;
      pu.u[2] = sel2 ? d2 : d0;
      pu.u[3] = sel2 ? d3 : d1;
      const short8 pa = pu.v;
#pragma unroll
      for (int nt = 0; nt < 4; ++nt) {
        const int vb_off = (nt * 16 + cc) * 128 + kc * 64 + hi * 16;
        short8 vb = *(const short8*)(VtB + (vb_off ^ ksw2));
        o[nt] = __builtin_amdgcn_mfma_f32_16x16x32_bf16(vb, pa, o[nt], 0, 0, 0);
      }
    }

    asm volatile("s_waitcnt lgkmcnt(0)" ::: "memory");
    __builtin_amdgcn_s_barrier();
  }

  const float invl = 1.0f / lsum;
#pragma unroll
  for (int nt = 0; nt < 4; ++nt) {
    u16x4 y = { f2bf(o[nt][0] * invl), f2bf(o[nt][1] * invl),
                f2bf(o[nt][2] * invl), f2bf(o[nt][3] * invl) };
    *(u16x4*)(Yb + hbase + (size_t)(q0w + cc) * C + nt * 16 + hi * 4) = y;
  }
}

// ---------------- proj GEMM: BN=64, fp32 out ----------------
__global__ __launch_bounds__(256, 2) void gemm_proj(
    const u16* __restrict__ A, const u16* __restrict__ W,
    const float* __restrict__ bias, float* __restrict__ Out) {
  const int K = 1024, N = 1024;
  __shared__ __attribute__((aligned(16))) u16 As[128 * 32];
  __shared__ __attribute__((aligned(16))) u16 Bs[64 * 32];
  const int tid = threadIdx.x;
  const int lane = tid & 63;
  const int hi = lane >> 4, cc = lane & 15;
  const int w = tid >> 6, wm = w >> 1, wn = w & 1;
  const int row0 = blockIdx.y * 128, col0 = blockIdx.x * 64;

  const int lr = tid >> 2;
  const int lk = (tid & 3) * 8;
  const u16* Ag0 = A + (size_t)(row0 + lr) * K + lk;
  const u16* Ag1 = A + (size_t)(row0 + 64 + lr) * K + lk;
  const u16* Wg0 = W + (size_t)(col0 + lr) * K + lk;
  u16* Al0 = As + tid * 8;
  u16* Al1 = As + 2048 + tid * 8;
  u16* Bl0 = Bs + tid * 8;

  f32x4 acc[4][2];
#pragma unroll
  for (int m = 0; m < 4; ++m)
#pragma unroll
    for (int n = 0; n < 2; ++n) acc[m][n] = f32x4{0.f, 0.f, 0.f, 0.f};

  for (int k0 = 0; k0 < K; k0 += 32) {
    __syncthreads();
    gl_lds16(Ag0 + k0, Al0);
    gl_lds16(Ag1 + k0, Al1);
    gl_lds16(Wg0 + k0, Bl0);
    __syncthreads();
    short8 a[4], b[2];
#pragma unroll
    for (int m = 0; m < 4; ++m)
      a[m] = *(const short8*)(As + (wm * 64 + m * 16 + cc) * 32 + hi * 8);
#pragma unroll
    for (int n = 0; n < 2; ++n)
      b[n] = *(const short8*)(Bs + (wn * 32 + n * 16 + cc) * 32 + hi * 8);
#pragma unroll
    for (int m = 0; m < 4; ++m)
#pragma unroll
      for (int n = 0; n < 2; ++n)
        acc[m][n] = __builtin_amdgcn_mfma_f32_16x16x32_bf16(a[m], b[n], acc[m][n], 0, 0, 0);
  }

#pragma unroll
  for (int n = 0; n < 2; ++n) {
    const int col = col0 + wn * 32 + n * 16 + cc;
    const float bb = bias[col];
#pragma unroll
    for (int m = 0; m < 4; ++m) {
      const int rw = row0 + wm * 64 + m * 16 + hi * 4;
#pragma unroll
      for (int r = 0; r < 4; ++r)
        Out[(size_t)(rw + r) * N + col] = acc[m][n][r] + bb;
    }
  }
}

extern "C" void kernel_launch(void* const* d_in, const int* in_sizes, int n_in,
                              void* d_out, int out_size, void* d_ws, size_t ws_size,
                              hipStream_t stream) {
  const float* x  = (const float*)d_in[0];
  const float* Wq = (const float*)d_in[1];
  const float* bq = (const float*)d_in[2];
  const float* Wk = (const float*)d_in[3];
  const float* bk = (const float*)d_in[4];
  const float* Wv = (const float*)d_in[5];
  const float* bv = (const float*)d_in[6];
  const float* Wp = (const float*)d_in[7];
  const float* bp = (const float*)d_in[8];
  float* out = (float*)d_out;

  const int B = 2, T = 2048, C = 1024;
  const int M = B * T;
  const size_t MC = (size_t)M * C;
  const size_t CC = (size_t)C * C;

  char* p = (char*)d_ws;
  u16* xb  = (u16*)p;  p += MC * 2;    // reused as Y after QKV GEMM
  u16* Wqb = (u16*)p;  p += CC * 2;
  u16* Wkb = (u16*)p;  p += CC * 2;
  u16* Wvb = (u16*)p;  p += CC * 2;
  u16* Wpb = (u16*)p;  p += CC * 2;
  u16* Qbb = (u16*)p;  p += MC * 2;
  u16* Kbb = (u16*)p;  p += MC * 2;
  u16* Vbb = (u16*)p;  p += MC * 2;
  float* cosT = (float*)p; p += (size_t)T * 32 * 4;
  float* sinT = (float*)p; p += (size_t)T * 32 * 4;

  rope_table<<<T * 32 / 256, 256, 0, stream>>>(cosT, sinT, T);
  const int n4x = (int)(MC / 4);
  const int n4tot = n4x + 4 * (int)(CC / 4);
  cvt_all<<<n4tot / 256, 256, 0, stream>>>(x, Wq, Wk, Wv, Wp, xb, Wqb, Wkb, Wvb, Wpb, n4x);

  dim3 gq(24, M / 128);
  gemm_qkv<<<gq, 256, 0, stream>>>(xb, Wqb, Wkb, Wvb, bq, bk, bv, cosT, sinT, Qbb, Kbb, Vbb);

  dim3 fg(T / 64, B * 16);
  flash_mfma<<<fg, 256, 0, stream>>>(Qbb, Kbb, Vbb, xb);   // Y -> xb (reuse)

  dim3 gp(C / 64, M / 128);
  gemm_proj<<<gp, 256, 0, stream>>>(xb, Wpb, bp, out);
}